// Round 3
// baseline (521.637 us; speedup 1.0000x reference)
//
#include <hip/hip_runtime.h>

// GraphConvLayer: B=32, C=64, T=64, V=325, Ks=2. f32 in/out, bf16 MFMA compute.
// out[b,c,t,v] = x[b,c,t,v] + bias[c]
//              + sum_i W0[i,c] x[b,i,t,v]
//              + sum_i W1[i,c] * (sum_u x[b,i,t,u] gso[v,u])
//
// R3: 2 blocks/CU via LDS scheduling, NO tr-reads (R2's tr-read mapping was
// wrong -> revert to R1's verified fragment logic everywhere).
//  - v-halved blocks (grid 4096, h=bid&1): Xt/Yt are 176 rows = 25.3 KB each.
//  - Yt aliases Xr's buffer: Phase-A B-frags (bX[11]) are preloaded to regs and
//    the v-half transpose (Xt) is done BEFORE Yt overwrites buf1.
//  - LDS = max(Xr 46.1K, Yt 25.3K) + Xt 25.3K = 71.4 KB -> 2 blocks/CU.
//  - launch_bounds(1024,8) caps VGPR at 64 (R1 measured 52) -> 32 waves/CU.

typedef __bf16 bf16x8 __attribute__((ext_vector_type(8)));
typedef float f32x4 __attribute__((ext_vector_type(4)));

#define XROW 360   // Xr row stride (elems): >=352, 180dw%32=20 -> 2-way banks max
#define TROW 72    // Xt/Yt row stride: >=64, 36dw%32=4 -> 2-way banks max
#define GROW 352   // gso_pad row stride (11 k-tiles of 32)

__device__ __forceinline__ float bf2f(unsigned short u) {
  union { unsigned int i; float f; } t;
  t.i = ((unsigned int)u) << 16;
  return t.f;
}
__device__ __forceinline__ unsigned short f2bf(float f) {
  union { float f; unsigned int i; } t;
  t.f = f;
  unsigned int u = t.i;
  unsigned int r = (u + 0x7fffu + ((u >> 16) & 1u)) >> 16;  // RNE
  return (unsigned short)r;
}

// Builds bf16 gso_pad[352][352] (zero-padded) and bf16 Wt[k][c][i] = weight[k][i][c].
__global__ void prep_kernel(const float* __restrict__ gso,
                            const float* __restrict__ weight,
                            unsigned short* __restrict__ gso_pad,
                            unsigned short* __restrict__ wt) {
  int idx = blockIdx.x * 256 + threadIdx.x;
  if (idx < 352 * 352) {
    int v = idx / 352, u = idx - v * 352;
    unsigned short val = 0;
    if (v < 325 && u < 325) val = f2bf(gso[v * 325 + u]);
    gso_pad[idx] = val;
  }
  if (idx < 2 * 64 * 64) {
    int k = idx >> 12, r = idx & 4095, c = r >> 6, i = r & 63;
    wt[idx] = f2bf(weight[(k << 12) | (i << 6) | c]);
  }
}

__global__ __launch_bounds__(1024, 8) void gconv_kernel(
    const float* __restrict__ x,
    const float* __restrict__ bias,
    const unsigned short* __restrict__ gso_pad,
    const unsigned short* __restrict__ wt,
    float* __restrict__ out) {
  // buf1: Xr[64][XROW] (stage1..preload), then Yt[176][TROW] (Phase A..B)
  __shared__ unsigned short buf1[64 * XROW];   // 46080 B
  __shared__ unsigned short Xt[176 * TROW];    // 25344 B (this block's v-half)
  unsigned short* const Xr = buf1;
  unsigned short* const Yt = buf1;

  const int bid = blockIdx.x;
  const int h = bid & 1;          // v-half: tiles [h*176, h*176+176)
  const int bt = bid >> 1;        // sibling pairs share (b,t) -> L2 reuse of x
  const int b = bt >> 6, t = bt & 63;
  const int tid = threadIdx.x;
  const int xbase = b * 1331200 + t * 325;  // + c*20800 + v (f32 elems)
  const int voff = h * 176;

  // ---- Stage 1: global f32 -> bf16 Xr (coalesced over u; full u range) ----
#pragma unroll 4
  for (int idx = tid; idx < 64 * 352; idx += 1024) {
    int c = idx / 352, u = idx - c * 352;
    float val = (u < 325) ? x[xbase + c * 20800 + u] : 0.f;
    Xr[c * XROW + u] = f2bf(val);
  }
  __syncthreads();

  const int wid = tid >> 6, lane = tid & 63;
  const int quad = lane >> 4, l16 = lane & 15;
  const int koff = quad * 8;  // A/B frag: k = s*32 + quad*8 + j

  // ---- Stage 2: transpose this block's v-half: Xt[vl][c] = Xr[c][voff+vl] ----
  for (int idx = tid; idx < 16 * 176; idx += 1024) {
    int c4 = idx / 176, vl = idx - c4 * 176;
    int c = c4 * 4, v = voff + vl;
    ushort4 w;
    w.x = Xr[(c + 0) * XROW + v];  // zero for v>=325 (padded cols)
    w.y = Xr[(c + 1) * XROW + v];
    w.z = Xr[(c + 2) * XROW + v];
    w.w = Xr[(c + 3) * XROW + v];
    *reinterpret_cast<ushort4*>(&Xt[vl * TROW + c]) = w;
  }

  // ---- Preload Phase-A B-frags from Xr (regs) before Yt overwrites buf1 ----
  const int cn = (wid & 3) * 16;  // Phase A n-tile (c); also reused as cb below
  bf16x8 bX[11];
#pragma unroll
  for (int s = 0; s < 11; ++s)
    bX[s] = *reinterpret_cast<const bf16x8*>(&Xr[(cn + l16) * XROW + s * 32 + koff]);
  __syncthreads();  // all Xr reads done; buf1 is now Yt

  // ---- Phase A: Yt[vl][c] = sum_u gso[voff+vl,u] * x[c][u]  (M=v, N=c, K=352) ----
  for (int lt = (wid >> 2); lt < 11; lt += 4) {
    const int vb = voff + lt * 16;
    const unsigned short* gp = &gso_pad[(vb + l16) * GROW + koff];
    f32x4 acc = {0.f, 0.f, 0.f, 0.f};
#pragma unroll
    for (int s = 0; s < 11; ++s) {
      bf16x8 ag = *reinterpret_cast<const bf16x8*>(gp + s * 32);  // A: gso row (L2-hot)
      acc = __builtin_amdgcn_mfma_f32_16x16x32_bf16(ag, bX[s], acc, 0, 0, 0);
    }
    const int vr = lt * 16 + quad * 4;  // C/D: row = local v, col = c
#pragma unroll
    for (int r = 0; r < 4; ++r)
      Yt[(vr + r) * TROW + cn + l16] = f2bf(acc[r]);  // lanes contiguous
  }
  __syncthreads();

  // ---- Phase B: out[c][v] = W0^T@X + W1^T@Y + bias + residual ----
  {
    const int cb = (wid & 3) * 16;  // m-tile (c)
    bf16x8 aW[4];                   // A-frags: k-concat [W0 i0..63 | W1 i0..63]
#pragma unroll
    for (int s = 0; s < 4; ++s)
      aW[s] = *reinterpret_cast<const bf16x8*>(
          &wt[((s >> 1) * 64 + cb + l16) * 64 + (s & 1) * 32 + koff]);
    float bias_f[4];
#pragma unroll
    for (int r = 0; r < 4; ++r) bias_f[r] = bias[cb + quad * 4 + r];

    for (int nloc = (wid >> 2); nloc < 11; nloc += 4) {
      const int vbl = nloc * 16;
      const unsigned short* tp = &Xt[(vbl + l16) * TROW + koff];
      const unsigned short* yp = &Yt[(vbl + l16) * TROW + koff];
      bf16x8 bx0 = *reinterpret_cast<const bf16x8*>(tp);
      bf16x8 bx1 = *reinterpret_cast<const bf16x8*>(tp + 32);
      bf16x8 by0 = *reinterpret_cast<const bf16x8*>(yp);
      bf16x8 by1 = *reinterpret_cast<const bf16x8*>(yp + 32);
      f32x4 acc = {0.f, 0.f, 0.f, 0.f};
      acc = __builtin_amdgcn_mfma_f32_16x16x32_bf16(aW[0], bx0, acc, 0, 0, 0);
      acc = __builtin_amdgcn_mfma_f32_16x16x32_bf16(aW[1], bx1, acc, 0, 0, 0);
      acc = __builtin_amdgcn_mfma_f32_16x16x32_bf16(aW[2], by0, acc, 0, 0, 0);
      acc = __builtin_amdgcn_mfma_f32_16x16x32_bf16(aW[3], by1, acc, 0, 0, 0);
      const int v = voff + vbl + l16;  // C/D: col = v, row = c
      if (v < 325) {
        // residual from Xt (same bf16-rounded value as before): x[c][v]
        ushort4 rx = *reinterpret_cast<const ushort4*>(
            &Xt[(vbl + l16) * TROW + cb + quad * 4]);
        const unsigned short rr[4] = {rx.x, rx.y, rx.z, rx.w};
#pragma unroll
        for (int r = 0; r < 4; ++r) {
          const int c = cb + quad * 4 + r;
          out[xbase + c * 20800 + v] = acc[r] + bias_f[r] + bf2f(rr[r]);
        }
      }
    }
  }
}

extern "C" void kernel_launch(void* const* d_in, const int* in_sizes, int n_in,
                              void* d_out, int out_size, void* d_ws, size_t ws_size,
                              hipStream_t stream) {
  const float* x      = (const float*)d_in[0];
  const float* gso    = (const float*)d_in[1];
  const float* weight = (const float*)d_in[2];
  const float* bias   = (const float*)d_in[3];
  unsigned short* gso_pad = (unsigned short*)d_ws;   // 352*352 bf16
  unsigned short* wt      = gso_pad + 352 * 352;     // 2*64*64 bf16

  prep_kernel<<<485, 256, 0, stream>>>(gso, weight, gso_pad, wt);
  gconv_kernel<<<4096, 1024, 0, stream>>>(x, bias, gso_pad, wt, (float*)d_out);
}

// Round 4
// 436.040 us; speedup vs baseline: 1.1963x; 1.1963x over previous
//
#include <hip/hip_runtime.h>

// GraphConvLayer: B=32, C=64, T=64, V=325, Ks=2. f32 in/out, bf16 MFMA compute.
// out[b,c,t,v] = x[b,c,t,v] + bias[c]
//              + sum_i W0[i,c] x[b,i,t,v]
//              + sum_i W1[i,c] * (sum_u x[b,i,t,u] gso[v,u])
//
// R4: VALU-instruction diet (R1/R3 showed occupancy 46%->89% changes nothing;
// VALUBusy*dur ~ 64us of issue -> stage-1 repack machinery is first-order).
//  - native (__bf16) casts -> HW v_cvt_pk_bf16_f32 (manual 5-op RNE removed)
//  - stage-1 dual-writes Xr[c][u] + transposed XY[u][c]: stage-2 pass and one
//    barrier eliminated; Phase A writes Y into XY[v][64..127] (disjoint cols)
//  - division-free stage-1 indexing (c = tid>>4, u = (tid&15)+16k)
//  - full-v blocks again (grid 2048): x read once, FETCH back to ~100MB
//  - LDS = Xr 46KB + XY[352][136] 93.5KB = 138.5KB, 1 block/CU (occ ~46%)

typedef __bf16 bf16x8 __attribute__((ext_vector_type(8)));
typedef float f32x4 __attribute__((ext_vector_type(4)));

#define XROW 360   // Xr row stride (elems): 180dw%32=20 -> benign banks
#define QROW 136   // XY row stride (elems): 68dw%32=4 -> same pattern as R1's TROW
#define GROW 352   // gso_pad row stride (11 k-tiles of 32)

__device__ __forceinline__ float bf2f(unsigned short u) {
  union { unsigned int i; float f; } t;
  t.i = ((unsigned int)u) << 16;
  return t.f;
}
__device__ __forceinline__ unsigned short f2bf_hw(float f) {
  __bf16 b = (__bf16)f;  // compiler emits v_cvt_pk_bf16_f32 (RNE)
  union { __bf16 b; unsigned short u; } t;
  t.b = b;
  return t.u;
}

// Builds bf16 gso_pad[352][352] (zero-padded) and bf16 Wt[k][c][i] = weight[k][i][c].
__global__ void prep_kernel(const float* __restrict__ gso,
                            const float* __restrict__ weight,
                            unsigned short* __restrict__ gso_pad,
                            unsigned short* __restrict__ wt) {
  int idx = blockIdx.x * 256 + threadIdx.x;
  if (idx < 352 * 352) {
    int v = idx / 352, u = idx - v * 352;
    unsigned short val = 0;
    if (v < 325 && u < 325) val = f2bf_hw(gso[v * 325 + u]);
    gso_pad[idx] = val;
  }
  if (idx < 2 * 64 * 64) {
    int k = idx >> 12, r = idx & 4095, c = r >> 6, i = r & 63;
    wt[idx] = f2bf_hw(weight[(k << 12) | (i << 6) | c]);
  }
}

__global__ __launch_bounds__(1024, 4) void gconv_kernel(
    const float* __restrict__ x,
    const float* __restrict__ bias,
    const unsigned short* __restrict__ gso_pad,
    const unsigned short* __restrict__ wt,
    float* __restrict__ out) {
  __shared__ unsigned short Xr[64 * XROW];   // 46080 B: x[c][u], u>=325 zero
  __shared__ unsigned short XY[352 * QROW];  // 95744 B: [u/v][ X c0..63 | Y c0..63 | pad ]

  const int bid = blockIdx.x;
  const int b = bid >> 6, t = bid & 63;
  const int tid = threadIdx.x;
  const int xbase = b * 1331200 + t * 325;  // + c*20800 + v (f32 elems)

  // ---- Stage 1: global f32 -> bf16, dual-write Xr[c][u] and XY[u][c] ----
  {
    const int c1 = tid >> 4;        // each thread owns one c row
    const int u0 = tid & 15;        // u = u0 + 16k, k = 0..21 covers 0..351
    const float* xrow = &x[xbase + c1 * 20800];
    unsigned short* xr = &Xr[c1 * XROW];
    unsigned short* xyc = &XY[c1];
#pragma unroll 11
    for (int k = 0; k < 22; ++k) {
      const int u = u0 + 16 * k;
      float val = (u < 325) ? xrow[u] : 0.f;
      unsigned short us = f2bf_hw(val);
      xr[u] = us;
      xyc[u * QROW] = us;
    }
  }
  __syncthreads();

  const int wid = tid >> 6, lane = tid & 63;
  const int quad = lane >> 4, l16 = lane & 15;
  const int koff = quad * 8;  // A/B frag: k = s*32 + quad*8 + j

  // ---- Phase A: XY[v][64+c] = sum_u gso[v,u] * x[c][u]  (M=v, N=c, K=352) ----
  {
    const int cn = (wid & 3) * 16;  // n-tile (c)
    bf16x8 bX[11];                  // B-frags: X rows, reused across all m-tiles
#pragma unroll
    for (int s = 0; s < 11; ++s)
      bX[s] = *reinterpret_cast<const bf16x8*>(&Xr[(cn + l16) * XROW + s * 32 + koff]);
    for (int lt = (wid >> 2); lt < 22; lt += 4) {
      const int vb = lt * 16;
      const unsigned short* gp = &gso_pad[(vb + l16) * GROW + koff];
      f32x4 acc = {0.f, 0.f, 0.f, 0.f};
#pragma unroll
      for (int s = 0; s < 11; ++s) {
        bf16x8 ag = *reinterpret_cast<const bf16x8*>(gp + s * 32);  // A: gso row (L2-hot)
        acc = __builtin_amdgcn_mfma_f32_16x16x32_bf16(ag, bX[s], acc, 0, 0, 0);
      }
      const int vr = vb + quad * 4;  // C/D: row = v, col = c
#pragma unroll
      for (int r = 0; r < 4; ++r)
        XY[(vr + r) * QROW + 64 + cn + l16] = f2bf_hw(acc[r]);
    }
  }
  __syncthreads();

  // ---- Phase B: out[c][v] = W0^T@X + W1^T@Y + bias + residual ----
  {
    const int cb = (wid & 3) * 16;  // m-tile (c)
    bf16x8 aW[4];                   // A-frags: k-concat [W0 i0..63 | W1 i0..63]
#pragma unroll
    for (int s = 0; s < 4; ++s)
      aW[s] = *reinterpret_cast<const bf16x8*>(
          &wt[((s >> 1) * 64 + cb + l16) * 64 + (s & 1) * 32 + koff]);
    float bias_f[4];
#pragma unroll
    for (int r = 0; r < 4; ++r) bias_f[r] = bias[cb + quad * 4 + r];

    for (int n = (wid >> 2); n < 22; n += 4) {
      const int vb = n * 16;
      const unsigned short* xyp = &XY[(vb + l16) * QROW];
      bf16x8 bx0 = *reinterpret_cast<const bf16x8*>(xyp + koff);
      bf16x8 bx1 = *reinterpret_cast<const bf16x8*>(xyp + 32 + koff);
      bf16x8 by0 = *reinterpret_cast<const bf16x8*>(xyp + 64 + koff);
      bf16x8 by1 = *reinterpret_cast<const bf16x8*>(xyp + 96 + koff);
      f32x4 acc = {0.f, 0.f, 0.f, 0.f};
      acc = __builtin_amdgcn_mfma_f32_16x16x32_bf16(aW[0], bx0, acc, 0, 0, 0);
      acc = __builtin_amdgcn_mfma_f32_16x16x32_bf16(aW[1], bx1, acc, 0, 0, 0);
      acc = __builtin_amdgcn_mfma_f32_16x16x32_bf16(aW[2], by0, acc, 0, 0, 0);
      acc = __builtin_amdgcn_mfma_f32_16x16x32_bf16(aW[3], by1, acc, 0, 0, 0);
      const int v = vb + l16;  // C/D: col = v, row = c
      if (v < 325) {
        // residual: bf16-rounded x[c][v] from XY X-part (8B aligned)
        ushort4 rx = *reinterpret_cast<const ushort4*>(xyp + cb + quad * 4);
        const unsigned short rr[4] = {rx.x, rx.y, rx.z, rx.w};
#pragma unroll
        for (int r = 0; r < 4; ++r) {
          const int c = cb + quad * 4 + r;
          out[xbase + c * 20800 + v] = acc[r] + bias_f[r] + bf2f(rr[r]);
        }
      }
    }
  }
}

extern "C" void kernel_launch(void* const* d_in, const int* in_sizes, int n_in,
                              void* d_out, int out_size, void* d_ws, size_t ws_size,
                              hipStream_t stream) {
  const float* x      = (const float*)d_in[0];
  const float* gso    = (const float*)d_in[1];
  const float* weight = (const float*)d_in[2];
  const float* bias   = (const float*)d_in[3];
  unsigned short* gso_pad = (unsigned short*)d_ws;   // 352*352 bf16
  unsigned short* wt      = gso_pad + 352 * 352;     // 2*64*64 bf16

  prep_kernel<<<485, 256, 0, stream>>>(gso, weight, gso_pad, wt);
  gconv_kernel<<<2048, 1024, 0, stream>>>(x, bias, gso_pad, wt, (float*)d_out);
}

// Round 5
// 385.124 us; speedup vs baseline: 1.3545x; 1.1322x over previous
//
#include <hip/hip_runtime.h>

// GraphConvLayer: B=32, C=64, T=64, V=325, Ks=2. f32 in/out, bf16 MFMA compute.
// out[b,c,t,v] = x[b,c,t,v] + bias[c]
//              + sum_i W0[i,c] x[b,i,t,v]
//              + sum_i W1[i,c] * (sum_u x[b,i,t,u] gso[v,u])
//
// R5: kill Phase A's 64-way gso gather.
//  - prep pre-swizzles gso into MFMA A-fragment order gfrag[mt][s][lane][j]
//    -> Phase A A-frag loads are 64-lane-contiguous 1KB coalesced (L2-hot).
//  - Phase A waves own TWO c-tiles (cn=(wid&1)*32, m-stride 8): gso read
//    redundancy 4x -> 2x, and acc0/acc1 interleave breaks the MFMA dep chain.
//  - everything else (stage1 dual-write, Phase B, residual) = R4 verified code.

typedef __bf16 bf16x8 __attribute__((ext_vector_type(8)));
typedef float f32x4 __attribute__((ext_vector_type(4)));

#define XROW 360   // Xr row stride (elems): 180dw%32=20 -> benign banks
#define QROW 136   // XY row stride (elems): 68dw%32=4 -> benign banks
#define NFRAG 512  // elems per gso frag: 64 lanes x 8

__device__ __forceinline__ float bf2f(unsigned short u) {
  union { unsigned int i; float f; } t;
  t.i = ((unsigned int)u) << 16;
  return t.f;
}
__device__ __forceinline__ unsigned short f2bf_hw(float f) {
  __bf16 b = (__bf16)f;  // compiler emits HW bf16 cvt (RNE)
  union { __bf16 b; unsigned short u; } t;
  t.b = b;
  return t.u;
}

// gfrag[((mt*11+s)*64+l)*8+j] = gso[mt*16+(l&15)][s*32+(l>>4)*8+j] (0-padded)
// wt[k][c][i] = weight[k][i][c]
__global__ void prep_kernel(const float* __restrict__ gso,
                            const float* __restrict__ weight,
                            unsigned short* __restrict__ gfrag,
                            unsigned short* __restrict__ wt) {
  int idx = blockIdx.x * 256 + threadIdx.x;
  if (idx < 22 * 11 * NFRAG) {
    int fid = idx >> 9, r = idx & 511;
    int l = r >> 3, j = r & 7;
    int mt = fid / 11, s = fid - 11 * mt;
    int v = (mt << 4) + (l & 15);
    int u = (s << 5) + ((l >> 4) << 3) + j;
    unsigned short val = 0;
    if (v < 325 && u < 325) val = f2bf_hw(gso[v * 325 + u]);
    gfrag[idx] = val;
  }
  if (idx < 2 * 64 * 64) {
    int k = idx >> 12, r = idx & 4095, c = r >> 6, i = r & 63;
    wt[idx] = f2bf_hw(weight[(k << 12) | (i << 6) | c]);
  }
}

__global__ __launch_bounds__(1024, 4) void gconv_kernel(
    const float* __restrict__ x,
    const float* __restrict__ bias,
    const unsigned short* __restrict__ gfrag,
    const unsigned short* __restrict__ wt,
    float* __restrict__ out) {
  __shared__ unsigned short Xr[64 * XROW];   // 46080 B: x[c][u], u>=325 zero
  __shared__ unsigned short XY[352 * QROW];  // 95744 B: [u/v][ X c0..63 | Y c0..63 | pad ]

  const int bid = blockIdx.x;
  const int b = bid >> 6, t = bid & 63;
  const int tid = threadIdx.x;
  const int xbase = b * 1331200 + t * 325;  // + c*20800 + v (f32 elems)

  // ---- Stage 1: global f32 -> bf16, dual-write Xr[c][u] and XY[u][c] ----
  {
    const int c1 = tid >> 4;        // each thread owns one c row
    const int u0 = tid & 15;        // u = u0 + 16k, k = 0..21 covers 0..351
    const float* xrow = &x[xbase + c1 * 20800];
    unsigned short* xr = &Xr[c1 * XROW];
    unsigned short* xyc = &XY[c1];
#pragma unroll 11
    for (int k = 0; k < 22; ++k) {
      const int u = u0 + 16 * k;
      float val = (u < 325) ? xrow[u] : 0.f;
      unsigned short us = f2bf_hw(val);
      xr[u] = us;
      xyc[u * QROW] = us;
    }
  }
  __syncthreads();

  const int wid = tid >> 6, lane = tid & 63;
  const int quad = lane >> 4, l16 = lane & 15;
  const int koff = quad * 8;  // A/B frag: k = s*32 + quad*8 + j

  // ---- Phase A: XY[v][64+c] = sum_u gso[v,u] * x[c][u]  (M=v, N=c, K=352) ----
  {
    const int cn = (wid & 1) * 32;  // this wave's two n-tiles: cn, cn+16
    bf16x8 bX0[11], bX1[11];        // B-frags: X rows, reused across all m-tiles
#pragma unroll
    for (int s = 0; s < 11; ++s) {
      bX0[s] = *reinterpret_cast<const bf16x8*>(&Xr[(cn + l16) * XROW + s * 32 + koff]);
      bX1[s] = *reinterpret_cast<const bf16x8*>(&Xr[(cn + 16 + l16) * XROW + s * 32 + koff]);
    }
    for (int mt = (wid >> 1); mt < 22; mt += 8) {
      const unsigned short* gp = &gfrag[(mt * 11) * NFRAG + lane * 8];
      f32x4 acc0 = {0.f, 0.f, 0.f, 0.f};
      f32x4 acc1 = {0.f, 0.f, 0.f, 0.f};
#pragma unroll
      for (int s = 0; s < 11; ++s) {
        // A-frag: 64 lanes contiguous, 1KB coalesced, L2-hot
        bf16x8 ag = *reinterpret_cast<const bf16x8*>(gp + s * NFRAG);
        acc0 = __builtin_amdgcn_mfma_f32_16x16x32_bf16(ag, bX0[s], acc0, 0, 0, 0);
        acc1 = __builtin_amdgcn_mfma_f32_16x16x32_bf16(ag, bX1[s], acc1, 0, 0, 0);
      }
      const int vr = mt * 16 + quad * 4;  // C/D: row = v, col = c
#pragma unroll
      for (int r = 0; r < 4; ++r) {
        XY[(vr + r) * QROW + 64 + cn + l16] = f2bf_hw(acc0[r]);
        XY[(vr + r) * QROW + 64 + cn + 16 + l16] = f2bf_hw(acc1[r]);
      }
    }
  }
  __syncthreads();

  // ---- Phase B: out[c][v] = W0^T@X + W1^T@Y + bias + residual ----
  {
    const int cb = (wid & 3) * 16;  // m-tile (c)
    bf16x8 aW[4];                   // A-frags: k-concat [W0 i0..63 | W1 i0..63]
#pragma unroll
    for (int s = 0; s < 4; ++s)
      aW[s] = *reinterpret_cast<const bf16x8*>(
          &wt[((s >> 1) * 64 + cb + l16) * 64 + (s & 1) * 32 + koff]);
    float bias_f[4];
#pragma unroll
    for (int r = 0; r < 4; ++r) bias_f[r] = bias[cb + quad * 4 + r];

    for (int n = (wid >> 2); n < 22; n += 4) {
      const int vb = n * 16;
      const unsigned short* xyp = &XY[(vb + l16) * QROW];
      bf16x8 bx0 = *reinterpret_cast<const bf16x8*>(xyp + koff);
      bf16x8 bx1 = *reinterpret_cast<const bf16x8*>(xyp + 32 + koff);
      bf16x8 by0 = *reinterpret_cast<const bf16x8*>(xyp + 64 + koff);
      bf16x8 by1 = *reinterpret_cast<const bf16x8*>(xyp + 96 + koff);
      f32x4 acc = {0.f, 0.f, 0.f, 0.f};
      acc = __builtin_amdgcn_mfma_f32_16x16x32_bf16(aW[0], bx0, acc, 0, 0, 0);
      acc = __builtin_amdgcn_mfma_f32_16x16x32_bf16(aW[1], bx1, acc, 0, 0, 0);
      acc = __builtin_amdgcn_mfma_f32_16x16x32_bf16(aW[2], by0, acc, 0, 0, 0);
      acc = __builtin_amdgcn_mfma_f32_16x16x32_bf16(aW[3], by1, acc, 0, 0, 0);
      const int v = vb + l16;  // C/D: col = v, row = c
      if (v < 325) {
        // residual: bf16-rounded x[c][v] from XY X-part (8B aligned)
        ushort4 rx = *reinterpret_cast<const ushort4*>(xyp + cb + quad * 4);
        const unsigned short rr[4] = {rx.x, rx.y, rx.z, rx.w};
#pragma unroll
        for (int r = 0; r < 4; ++r) {
          const int c = cb + quad * 4 + r;
          out[xbase + c * 20800 + v] = acc[r] + bias_f[r] + bf2f(rr[r]);
        }
      }
    }
  }
}

extern "C" void kernel_launch(void* const* d_in, const int* in_sizes, int n_in,
                              void* d_out, int out_size, void* d_ws, size_t ws_size,
                              hipStream_t stream) {
  const float* x      = (const float*)d_in[0];
  const float* gso    = (const float*)d_in[1];
  const float* weight = (const float*)d_in[2];
  const float* bias   = (const float*)d_in[3];
  unsigned short* gfrag = (unsigned short*)d_ws;       // 22*11*512 bf16 = 352*352
  unsigned short* wt    = gfrag + 22 * 11 * NFRAG;     // 2*64*64 bf16

  prep_kernel<<<485, 256, 0, stream>>>(gso, weight, gfrag, wt);
  gconv_kernel<<<2048, 1024, 0, stream>>>(x, bias, gfrag, wt, (float*)d_out);
}